// Round 1
// 35416.956 us; speedup vs baseline: 1.3825x; 1.3825x over previous
//
#include <hip/hip_runtime.h>
#include <hip/hip_bf16.h>

// Problem constants
#define T_STEPS 512
#define ASTR    712            // LDS A-row stride in bf16 elems (704 + 8 pad, 16B-aligned rows)
#define LOG2PI  1.8378770664093453f

typedef short  short8   __attribute__((ext_vector_type(8)));
typedef short  short4v  __attribute__((ext_vector_type(4)));
typedef float  floatx16 __attribute__((ext_vector_type(16)));
typedef unsigned short u16;

// ws layout: pre-swizzled bf16 B-fragments, offsets in short8 (16B) units
#define VOFF_R  0              // r-gate  : [16 ntile][44 ktile][64 lane][8]  (K=704: W_ih|W_hh)
#define VOFF_Z  45056          // z-gate  : same shape
#define VOFF_N  90112          // i_n     : [16][12][64][8]                  (K=192: W_ih only)
#define VOFF_H  102400         // h_n     : [16][32][64][8]                  (K=512: W_hh only)
#define VOFF_LS 135168         // loc/scale: [4][32][64][8]                  (K=512, N=128)
#define VTOT    143360         // * 16B = 2,293,760 bytes of ws

// output offsets (floats)
#define EOFF 67108864ULL
#define LOFF 68157440ULL

static __device__ __forceinline__ u16 f2bf(float f) {
  __hip_bfloat16 h = __float2bfloat16(f);
  return *reinterpret_cast<u16*>(&h);
}

// ---------------------------------------------------------------------------
// Phase 0: swizzle fp32 weights -> bf16 B-fragment order (runs every launch;
// ws is re-poisoned by the harness before every timed call).
// B[k][n] = W[n][k] for the x@W^T gate GEMMs; W_loc/W_scale are already [K][N].
// Fragment map (32x32x16): lane holds B[k = kt*16 + (lane>>5)*8 + e][n = nt*32 + (lane&31)]
// ---------------------------------------------------------------------------
__global__ __launch_bounds__(256) void swizzle_kernel(
    const float* __restrict__ W_ih, const float* __restrict__ W_hh,
    const float* __restrict__ W_loc, const float* __restrict__ W_scale,
    u16* __restrict__ ws)
{
  int gid = blockIdx.x * 256 + threadIdx.x;
  if (gid >= VTOT) return;
  const int l   = gid & 63;
  const int n_l = l & 31;
  const int k_h = (l >> 5) * 8;
  float src[8];

  if (gid < VOFF_Z) {                       // r gate, KT=44
    int r = gid >> 6; int kt = r % 44; int nt = r / 44;
    int j = nt * 32 + n_l;                  // gate row 0..511
    int k0 = kt * 16 + k_h;
    #pragma unroll
    for (int e = 0; e < 8; ++e) { int k = k0 + e;
      src[e] = (k < 192) ? W_ih[j * 192 + k] : W_hh[j * 512 + (k - 192)]; }
  } else if (gid < VOFF_N) {                // z gate
    int r = (gid - VOFF_Z) >> 6; int kt = r % 44; int nt = r / 44;
    int j = 512 + nt * 32 + n_l;
    int k0 = kt * 16 + k_h;
    #pragma unroll
    for (int e = 0; e < 8; ++e) { int k = k0 + e;
      src[e] = (k < 192) ? W_ih[j * 192 + k] : W_hh[j * 512 + (k - 192)]; }
  } else if (gid < VOFF_H) {                // i_n, KT=12 (K=192)
    int r = (gid - VOFF_N) >> 6; int kt = r % 12; int nt = r / 12;
    int j = 1024 + nt * 32 + n_l;
    int k0 = kt * 16 + k_h;
    #pragma unroll
    for (int e = 0; e < 8; ++e) src[e] = W_ih[j * 192 + k0 + e];
  } else if (gid < VOFF_LS) {               // h_n, KT=32 (K=512, A col = 192 + k)
    int r = (gid - VOFF_H) >> 6; int kt = r % 32; int nt = r / 32;
    int j = 1024 + nt * 32 + n_l;
    int k0 = kt * 16 + k_h;
    #pragma unroll
    for (int e = 0; e < 8; ++e) src[e] = W_hh[j * 512 + k0 + e];
  } else {                                  // loc|scale: B[k][n], n<64 loc else scale
    int r = (gid - VOFF_LS) >> 6; int kt = r % 32; int nt = r / 32;
    int n = nt * 32 + n_l;
    int k0 = kt * 16 + k_h;
    #pragma unroll
    for (int e = 0; e < 8; ++e) { int k = k0 + e;
      src[e] = (n < 64) ? W_loc[k * 64 + n] : W_scale[k * 64 + (n - 64)]; }
  }

  short8 v;
  #pragma unroll
  for (int e = 0; e < 8; ++e) v[e] = (short)f2bf(src[e]);
  reinterpret_cast<short8*>(ws)[gid] = v;
}

// ---------------------------------------------------------------------------
// Phase 1: persistent recurrence. 64 blocks x 1024 threads (16 waves).
// Block owns 32 rows; wave wv owns gate N-tile nt = wv (32 gate cols).
// Accumulators per wave: 64 VGPRs (was 256) -> compiler has headroom to batch
// the L2 weight-fragment loads; 4 waves/SIMD hide the remaining latency.
// ---------------------------------------------------------------------------
__global__ __launch_bounds__(1024, 4) void rnn_kernel(
    const float* __restrict__ y,      const float* __restrict__ b_ih,
    const float* __restrict__ b_hh,   const float* __restrict__ b_loc,
    const float* __restrict__ b_scale,const float* __restrict__ noise,
    const u16*  __restrict__ ws,      float* __restrict__ out)
{
  __shared__ u16   Abuf[32 * ASTR];   // [32 rows][ y(128) | ll(64) | h(512) | pad(8) ] bf16
  __shared__ float scS[32][64];       // scale exchange: waves 2/3 -> waves 0/1
  __shared__ float entP[2][32];
  __shared__ float lpP[2][32];

  const int tid     = threadIdx.x;
  const int wv      = tid >> 6;       // wave 0..15
  const int lane    = tid & 63;
  const int l31     = lane & 31;
  const int lhi     = lane >> 5;      // 0/1
  const int rowbase = blockIdx.x * 32;

  const short8* __restrict__ wsv = reinterpret_cast<const short8*>(ws);

  // zero A (h0 = 0, l0 = 0); y cols overwritten below
  for (int i = tid; i < 32 * ASTR; i += 1024) Abuf[i] = 0;

  // per-lane biases for this wave's gate N-tile: j = wv*32 + l31
  const int jg = wv * 32 + l31;
  const float bR = b_ih[jg]        + b_hh[jg];
  const float bZ = b_ih[512 + jg]  + b_hh[512 + jg];
  const float bN = b_ih[1024 + jg];
  const float bH = b_hh[1024 + jg];
  float bL = 0.f, bS = 0.f;
  if (wv < 2)      bL = b_loc[jg];           // loc cols 0..63
  else if (wv < 4) bS = b_scale[jg - 64];    // scale cols 0..63

  // fp32 GRU state held in registers; lane owns (m = (q&3)+8*(q>>2)+4*lhi, jg)
  float h[16];
  #pragma unroll
  for (int q = 0; q < 16; ++q) h[q] = 0.f;

  // y loader: threads 256..511 (waves 4..7) stage y[:, tt, :] for 32 b-rows
  auto loadY = [&](int tt) {
    if ((tid >> 8) != 1) return;
    int tid2 = tid & 255;
    int m    = tid2 >> 3;               // 0..31
    int cg   = tid2 & 7;                // 0..7, 16 cols each
    int b    = (rowbase + m) & 255;
    const float4* src = reinterpret_cast<const float4*>(&y[((size_t)b * 512 + tt) * 128]) + cg * 4;
    u16* dst = &Abuf[m * ASTR + cg * 16];
    #pragma unroll
    for (int i = 0; i < 4; ++i) {
      float4 v = src[i];
      short4v pv;
      pv[0] = (short)f2bf(v.x); pv[1] = (short)f2bf(v.y);
      pv[2] = (short)f2bf(v.z); pv[3] = (short)f2bf(v.w);
      *reinterpret_cast<short4v*>(dst + i * 4) = pv;
    }
  };

  __syncthreads();
  loadY(0);
  __syncthreads();

  // weight streams for this wave
  const short8* __restrict__ pR = wsv + VOFF_R + (size_t)wv * 44 * 64 + lane;
  const short8* __restrict__ pZ = wsv + VOFF_Z + (size_t)wv * 44 * 64 + lane;
  const short8* __restrict__ pN = wsv + VOFF_N + (size_t)wv * 12 * 64 + lane;
  const short8* __restrict__ pH = wsv + VOFF_H + (size_t)wv * 32 * 64 + lane;
  const short8* __restrict__ pX = wsv + VOFF_LS + (size_t)(wv < 4 ? wv : 0) * 32 * 64 + lane;

  for (int t = 0; t < T_STEPS; ++t) {
    // ---- gate GEMM (reads Abuf = [y_t | ll_{t-1} | h_{t-1}]) + in-register update ----
    floatx16 aR, aZ, aN, aH;
    #pragma unroll
    for (int q = 0; q < 16; ++q) { aR[q] = 0.f; aZ[q] = 0.f; aN[q] = 0.f; aH[q] = 0.f; }

    #pragma unroll 4
    for (int kt = 0; kt < 12; ++kt) {           // K-chunks covering y|ll (and r/z)
      short8 af = *reinterpret_cast<const short8*>(&Abuf[l31 * ASTR + kt * 16 + lhi * 8]);
      aR = __builtin_amdgcn_mfma_f32_32x32x16_bf16(af, pR[kt * 64], aR, 0, 0, 0);
      aZ = __builtin_amdgcn_mfma_f32_32x32x16_bf16(af, pZ[kt * 64], aZ, 0, 0, 0);
      aN = __builtin_amdgcn_mfma_f32_32x32x16_bf16(af, pN[kt * 64], aN, 0, 0, 0);
    }
    #pragma unroll 4
    for (int kt = 12; kt < 44; ++kt) {          // K-chunks covering h (and r/z)
      short8 af = *reinterpret_cast<const short8*>(&Abuf[l31 * ASTR + kt * 16 + lhi * 8]);
      aR = __builtin_amdgcn_mfma_f32_32x32x16_bf16(af, pR[kt * 64], aR, 0, 0, 0);
      aZ = __builtin_amdgcn_mfma_f32_32x32x16_bf16(af, pZ[kt * 64], aZ, 0, 0, 0);
      aH = __builtin_amdgcn_mfma_f32_32x32x16_bf16(af, pH[(kt - 12) * 64], aH, 0, 0, 0);
    }
    // GRU update (h_old in registers; nothing written to Abuf yet)
    #pragma unroll
    for (int q = 0; q < 16; ++q) {
      float r  = 1.f / (1.f + __expf(-(aR[q] + bR)));
      float z  = 1.f / (1.f + __expf(-(aZ[q] + bZ)));
      float nv = tanhf(aN[q] + bN + r * (aH[q] + bH));
      h[q] = (1.f - z) * nv + z * h[q];
    }
    __syncthreads();   // B1: everyone done reading old h/ll/y from Abuf

    // publish h_t (bf16) to Abuf cols 192..703 (each wave its 32 cols)
    #pragma unroll
    for (int q = 0; q < 16; ++q) {
      int m = (q & 3) + 8 * (q >> 2) + 4 * lhi;
      Abuf[m * ASTR + 192 + jg] = f2bf(h[q]);
    }
    __syncthreads();   // B2: h_t visible

    // ---- loc/scale GEMM on h_t, split over 4 waves (N-tiles of [loc|scale]) ----
    floatx16 aX;
    if (wv < 4) {
      #pragma unroll
      for (int q = 0; q < 16; ++q) aX[q] = 0.f;
      #pragma unroll 4
      for (int kt = 0; kt < 32; ++kt) {
        short8 af = *reinterpret_cast<const short8*>(&Abuf[l31 * ASTR + 192 + kt * 16 + lhi * 8]);
        aX = __builtin_amdgcn_mfma_f32_32x32x16_bf16(af, pX[kt * 64], aX, 0, 0, 0);
      }
      if (wv >= 2) {
        // waves 2/3: softplus(scale) -> LDS exchange
        #pragma unroll
        for (int q = 0; q < 16; ++q) {
          int m = (q & 3) + 8 * (q >> 2) + 4 * lhi;
          float sarg = aX[q] + bS;
          float sc   = fmaxf(sarg, 0.f) + log1pf(__expf(-fabsf(sarg)));  // softplus
          scS[m][jg - 64] = sc;
        }
      }
    } else if (wv < 8) {
      if (t + 1 < T_STEPS) loadY(t + 1);        // waves 4..7 prefetch y[t+1] (cols 0..127)
    }
    __syncthreads();   // B2b: sc visible (and y_{t+1} staged)

    if (wv < 2) {
      // waves 0/1 hold loc in aX; combine with sc, sample, reduce
      #pragma unroll
      for (int q = 0; q < 16; ++q) {
        int m  = (q & 3) + 8 * (q >> 2) + 4 * lhi;
        int sb = rowbase + m;
        float sc  = scS[m][jg];
        float lg  = __logf(sc);
        float ep  = noise[(size_t)t * 131072 + (size_t)sb * 64 + jg];
        float llv = aX[q] + bL + sc * ep;
        out[((size_t)sb * 512 + t) * 64 + jg] = llv;                    // x_samples
        Abuf[m * ASTR + 128 + jg] = f2bf(llv);                          // ll feedback
        float eV = lg;
        float lV = -0.5f * ep * ep - lg;
        #pragma unroll
        for (int off = 1; off < 32; off <<= 1) {                        // sum over 32 j-lanes
          eV += __shfl_xor(eV, off, 64);
          lV += __shfl_xor(lV, off, 64);
        }
        if (l31 == 0) { entP[wv][m] = eV; lpP[wv][m] = lV; }
      }
    }
    __syncthreads();   // B3: ll_t + partial reductions visible

    if (tid < 32) {
      int sb  = rowbase + tid;
      float e = entP[0][tid] + entP[1][tid];
      float l = lpP[0][tid] + lpP[1][tid];
      out[EOFF + (size_t)sb * 512 + t] = 32.f * (1.f + LOG2PI) + e;     // entropies
      out[LOFF + (size_t)sb * 512 + t] = l - 32.f * LOG2PI;            // log_probs
    }
    // no barrier needed: entP rewritten only after B2b of t+1; Abuf writes of
    // t+1 (h publish) are behind B1 of t+1.
  }
}

extern "C" void kernel_launch(void* const* d_in, const int* in_sizes, int n_in,
                              void* d_out, int out_size, void* d_ws, size_t ws_size,
                              hipStream_t stream) {
  (void)in_sizes; (void)n_in; (void)out_size; (void)ws_size;
  const float* y       = (const float*)d_in[0];
  const float* W_ih    = (const float*)d_in[1];
  const float* W_hh    = (const float*)d_in[2];
  const float* b_ih    = (const float*)d_in[3];
  const float* b_hh    = (const float*)d_in[4];
  const float* W_loc   = (const float*)d_in[5];
  const float* b_loc   = (const float*)d_in[6];
  const float* W_scale = (const float*)d_in[7];
  const float* b_scale = (const float*)d_in[8];
  const float* noise   = (const float*)d_in[9];
  u16*   ws  = (u16*)d_ws;      // needs 2,293,760 bytes
  float* out = (float*)d_out;

  hipLaunchKernelGGL(swizzle_kernel, dim3((VTOT + 255) / 256), dim3(256), 0, stream,
                     W_ih, W_hh, W_loc, W_scale, ws);
  hipLaunchKernelGGL(rnn_kernel, dim3(64), dim3(1024), 0, stream,
                     y, b_ih, b_hh, b_loc, b_scale, noise, ws, out);
}